// Round 7
// baseline (399.927 us; speedup 1.0000x reference)
//
#include <hip/hip_runtime.h>
#include <hip/hip_bf16.h>
#include <math.h>

#define B_ROWS 1024
#define DDIM   512
#define CN     51332
#define EPSF   1e-3f
#define SCALE  64.0f
#define NT     8       /* K-steps of 64 */

typedef unsigned short ushort_t;
typedef short bf16x8 __attribute__((ext_vector_type(8)));   // 8 bf16 (4 VGPRs)
typedef float f32x4  __attribute__((ext_vector_type(4)));   // 4 fp32 acc
typedef unsigned short us8 __attribute__((ext_vector_type(8)));
typedef unsigned short us4 __attribute__((ext_vector_type(4)));

static __device__ __forceinline__ unsigned short f2bf(float f) {
    // round-to-nearest-even fp32 -> bf16 (inputs are finite)
    unsigned int u = __float_as_uint(f);
    u += 0x7fffu + ((u >> 16) & 1u);
    return (unsigned short)(u >> 16);
}

__global__ void embcast(const float* __restrict__ emb, ushort_t* __restrict__ embb) {
    const int t = blockIdx.x * 256 + threadIdx.x;    // 4 elems/thread
    const float4 v = ((const float4*)emb)[t];
    us4 o; o[0] = f2bf(v.x); o[1] = f2bf(v.y); o[2] = f2bf(v.z); o[3] = f2bf(v.w);
    *(us4*)&embb[(size_t)t * 4] = o;
}

// ---------------------------------------------------------------------------
// Fused 256x128 counted-vmcnt bf16 MFMA GEMM reading B DIRECTLY from fp32 kern
// ([d][c] layout) — eliminates the colpass/kbT round-trip (53 MB write +
// 53 MB read) and folds column sumsq into the staging path.
//   - A (embb bf16) staged via global_load_lds, pre-swizzled source.
//   - B: per K-step each thread owns (col = tid&127, dgrp = tid>>7): loads 16
//     fp32 scalars (coalesced 256 B/wave along c), casts, ds_writes 2 us8
//     k-contiguous chunks at chunk^(col&7) swizzle — bank-balanced b128.
//   - COLUMN CLAMP (not predication!): OOB lanes broadcast-read col CN-1 so
//     EVERY wave issues exactly 16 B-loads/step — per-lane exec-masking would
//     let all-invalid waves skip loads (s_cbranch_execz) and break the vmcnt
//     FIFO, crossing barriers before their A-DMA landed (silent corruption).
//     Junk values are masked at the epilogue (invn=0, store guard).
//   - 2-deep B reg pipeline: B(t+2) loads issued at t.P0, ds_written at t+1.P1.
//   - FIFO per step: [B(t+1)16, A(t+1)4, B(t+2)16, A(t+2)4]; single counted
//     s_waitcnt vmcnt(20) at P1 drains exactly {B(t+1), A(t+1)}. Never 0.
//   - Column sumsq accumulated at write sites (each real k-chunk once; wrap
//     restage at t=7 skipped), LDS-reduced in epilogue -> inv_norm in-kernel.
#define MFMA(d, va, vb) (d) = __builtin_amdgcn_mfma_f32_16x16x32_bf16((va), (vb), (d), 0, 0, 0)

#define STAGE16(gp, lp) __builtin_amdgcn_global_load_lds( \
    (__attribute__((address_space(1))) void*)(gp), \
    (__attribute__((address_space(3))) void*)(lp), 16, 0, 0)

#define STAGE(gl, sb, half, kstep) do { \
    const int rb_ = (half) * 128 + w * 16; \
    STAGE16((gl) + (size_t)rb_ * DDIM + (size_t)(kstep) * 64, &(sb)[rb_ * 64]); \
    STAGE16((gl) + (size_t)(rb_ + 8) * DDIM + (size_t)(kstep) * 64, &(sb)[(rb_ + 8) * 64]); \
} while (0)

// one K-step: kN = (t+2)&7 (stage index for BOTH A and B-loads), vbL = reg set
// receiving B(t+2), vbW = reg set holding B(t+1) to write, doSum = (t < NT-1).
#define KSTEP(kN, vbL, vbW, Sa, Sb, SbN, doSum) do { \
    bf16x8 a_[4][2], b0_[2][2], b1_[2][2]; \
    /* P0: ds_read all-A + B[j0,j1] | issue B-loads | MFMA j0-1 */ \
    _Pragma("unroll") for (int i = 0; i < 4; ++i) { \
        a_[i][0] = *(const bf16x8*)&Sa[offA + i * 1024 + ca0]; \
        a_[i][1] = *(const bf16x8*)&Sa[offA + i * 1024 + ca1]; } \
    _Pragma("unroll") for (int j = 0; j < 2; ++j) { \
        b0_[j][0] = *(const bf16x8*)&Sb[offB + j * 1024 + ca0]; \
        b0_[j][1] = *(const bf16x8*)&Sb[offB + j * 1024 + ca1]; } \
    _Pragma("unroll") for (int j = 0; j < 16; ++j) \
        vbL[j] = gB[(size_t)((kN) * 64 + j) * CN]; \
    __builtin_amdgcn_sched_barrier(0);  /* pin B-load issue before barrier */ \
    __builtin_amdgcn_s_barrier(); \
    __builtin_amdgcn_s_setprio(1); \
    _Pragma("unroll") for (int i = 0; i < 4; ++i) \
    _Pragma("unroll") for (int j = 0; j < 2; ++j) { \
        MFMA(acc[i][j], a_[i][0], b0_[j][0]); \
        MFMA(acc[i][j], a_[i][1], b0_[j][1]); } \
    __builtin_amdgcn_s_setprio(0); \
    __builtin_amdgcn_s_barrier(); \
    __builtin_amdgcn_sched_barrier(0); \
    /* P1: ds_read B[j2,j3] | stage A(t+2) | MFMA j2-3 | vmcnt(20) | ds_write B(t+1) */ \
    _Pragma("unroll") for (int j = 0; j < 2; ++j) { \
        b1_[j][0] = *(const bf16x8*)&Sb[offB + (j + 2) * 1024 + ca0]; \
        b1_[j][1] = *(const bf16x8*)&Sb[offB + (j + 2) * 1024 + ca1]; } \
    STAGE(gAl, Sa, 0, kN); STAGE(gAl, Sa, 1, kN); \
    __builtin_amdgcn_s_barrier(); \
    __builtin_amdgcn_s_setprio(1); \
    _Pragma("unroll") for (int i = 0; i < 4; ++i) \
    _Pragma("unroll") for (int j = 0; j < 2; ++j) { \
        MFMA(acc[i][j + 2], a_[i][0], b1_[j][0]); \
        MFMA(acc[i][j + 2], a_[i][1], b1_[j][1]); } \
    __builtin_amdgcn_s_setprio(0); \
    asm volatile("s_waitcnt vmcnt(20)" ::: "memory"); \
    { us8 p0_, p1_; \
      _Pragma("unroll") for (int e = 0; e < 8; ++e) { \
          p0_[e] = f2bf(vbW[e]); p1_[e] = f2bf(vbW[8 + e]); } \
      *(us8*)&SbN[bo0] = p0_; *(us8*)&SbN[bo1] = p1_; \
      if (doSum) { \
          _Pragma("unroll") for (int e = 0; e < 16; ++e) sumsq += vbW[e] * vbW[e]; } } \
    asm volatile("s_waitcnt lgkmcnt(0)" ::: "memory"); \
    __builtin_amdgcn_s_barrier(); \
    __builtin_amdgcn_sched_barrier(0); \
} while (0)

__global__ __launch_bounds__(512, 2) void gemm_fused(
        const ushort_t* __restrict__ embb, const float* __restrict__ kern,
        float* __restrict__ out) {
    __shared__ ushort_t smem[49152];    // 96 KB: A[2][16384] | B[2][8192] (ushorts)

    const int tid  = threadIdx.x;
    const int lane = tid & 63;
    const int w    = tid >> 6;                 // wave 0..7
    const int wm = w >> 1, wn = w & 1;         // 4m x 2n wave grid
    const int lm = lane & 15, lq = lane >> 4;  // MFMA row-sel / quad
    const int r8 = lane >> 3, c8 = lane & 7;   // A-staging lane -> (row, 16B chunk)

    // exact XCD swizzle: 1608 = 8 x 201; m-fast so 4 consecutive blocks in an
    // XCD share one kern panel (256 KB fp32 << 4 MB XCD L2).
    const int bid = blockIdx.x;
    const int u   = (bid & 7) * 201 + (bid >> 3);
    const int m0  = (u & 3) * 256;
    const int n0  = (u >> 2) * 128;            // 0..401 tiles

    const ushort_t* gAl = embb + (size_t)(m0 + r8) * DDIM + ((c8 ^ r8) << 3);

    // B ownership: thread -> (column, 16-d group). Pointer CLAMPED, never
    // predicated (see header comment): all waves issue the full load count.
    const int colL = (w & 1) * 64 + lane;      // 0..127  (== tid & 127)
    const int dgrp = w >> 1;                   // 0..3
    const int gcol = n0 + colL;
    const int gcolc = (gcol < CN) ? gcol : (CN - 1);
    const float* gB = kern + (size_t)(dgrp * 16) * CN + gcolc;
    const int bws = colL * 64;                 // this col's LDS row (ushorts)
    const int bo0 = bws + (((dgrp * 2    ) ^ (colL & 7)) << 3);
    const int bo1 = bws + (((dgrp * 2 + 1) ^ (colL & 7)) << 3);

    // ds_read swizzle (row&7 == lm&7 for both A and B rows)
    const int swz = lm & 7;
    const int ca0 = ((lq    ) ^ swz) << 3;
    const int ca1 = ((lq + 4) ^ swz) << 3;
    const int offA = (wm * 64 + lm) * 64;
    const int offB = (wn * 64 + lm) * 64;

    f32x4 acc[4][4];
#pragma unroll
    for (int i = 0; i < 4; ++i)
#pragma unroll
        for (int j = 0; j < 4; ++j) acc[i][j] = (f32x4){0.f, 0.f, 0.f, 0.f};

    ushort_t* A0 = smem;             // A bufs: 16384 ushorts each (32 KB)
    ushort_t* A1 = smem + 16384;
    ushort_t* B0 = smem + 32768;     // B bufs: 8192 ushorts each (16 KB)
    ushort_t* B1 = smem + 40960;

    float sumsq = 0.f;
    float vb0[16], vb1[16];

    // prologue FIFO: [B(0)16, A(0)4, A(1)4, B(1)16]; vmcnt(20) drains B0+A0,
    // leaves [A(1)4, B(1)16] = 20 = the steady-state invariant.
#pragma unroll
    for (int j = 0; j < 16; ++j)
        vb0[j] = gB[(size_t)j * CN];
    __builtin_amdgcn_sched_barrier(0);
    STAGE(gAl, A0, 0, 0); STAGE(gAl, A0, 1, 0);
    __builtin_amdgcn_sched_barrier(0);
    STAGE(gAl, A1, 0, 1); STAGE(gAl, A1, 1, 1);
    __builtin_amdgcn_sched_barrier(0);
#pragma unroll
    for (int j = 0; j < 16; ++j)
        vb1[j] = gB[(size_t)(64 + j) * CN];
    __builtin_amdgcn_sched_barrier(0);
    asm volatile("s_waitcnt vmcnt(20)" ::: "memory");
    {
        us8 p0_, p1_;
#pragma unroll
        for (int e = 0; e < 8; ++e) { p0_[e] = f2bf(vb0[e]); p1_[e] = f2bf(vb0[8 + e]); }
        *(us8*)&B0[bo0] = p0_; *(us8*)&B0[bo1] = p1_;
#pragma unroll
        for (int e = 0; e < 16; ++e) sumsq += vb0[e] * vb0[e];
    }
    asm volatile("s_waitcnt lgkmcnt(0)" ::: "memory");
    __builtin_amdgcn_s_barrier();
    __builtin_amdgcn_sched_barrier(0);

    // main loop, 2x unrolled for static vb0/vb1 role swap (rule: no runtime
    // indexing of reg arrays). Even t: read A0/B0, load->vb0, write vb1->B1.
    for (int tt = 0; tt < NT / 2; ++tt) {
        const int t0 = 2 * tt, t1 = 2 * tt + 1;
        KSTEP((t0 + 2) & 7, vb0, vb1, A0, B0, B1, true);
        KSTEP((t1 + 2) & 7, vb1, vb0, A1, B1, B0, (t1 < NT - 1));
    }

    // ---- epilogue: drain stragglers; reduce sumsq -> inv_norm in LDS; then
    // wave-private swizzled staging (4 KiB/wave) -> coalesced 16B stores.
    asm volatile("s_waitcnt vmcnt(0)" ::: "memory");
    __syncthreads();
    float* sq    = (float*)(smem + 32768);     // B0 region: 512 floats
    float* inv_s = (float*)(smem + 40960);     // B1 region: 128 floats
    sq[dgrp * 128 + colL] = sumsq;
    __syncthreads();
    if (tid < 128) {
        const float tot = sq[tid] + sq[tid + 128] + sq[tid + 256] + sq[tid + 384];
        inv_s[tid] = 1.0f / fmaxf(sqrtf(tot), 1e-5f);
    }
    __syncthreads();

    float invn[4];
#pragma unroll
    for (int j = 0; j < 4; ++j) {
        const int col = n0 + wn * 64 + j * 16 + lm;
        invn[j] = (col < CN) ? inv_s[wn * 64 + j * 16 + lm] : 0.f;
    }
    float* Ew = (float*)smem + w * 1024;        // 16 x 64 f32 in A region
    const int rr = lane >> 4, cc = lane & 15;
#pragma unroll
    for (int i = 0; i < 4; ++i) {
#pragma unroll
        for (int j = 0; j < 4; ++j)
#pragma unroll
            for (int r = 0; r < 4; ++r) {
                const int row = lq * 4 + r;                     // 0..15
                const int cs  = ((j * 16 + lm) + row * 4) & 63; // swizzle
                float v = acc[i][j][r] * invn[j];
                v = fminf(fmaxf(v, -(1.0f - EPSF)), 1.0f - EPSF) * SCALE;
                Ew[row * 64 + cs] = v;
            }
#pragma unroll
        for (int rep = 0; rep < 4; ++rep) {
            const int row = rep * 4 + rr;                       // 0..15
            const f32x4 v = *(const f32x4*)&Ew[row * 64 + ((cc + row) & 15) * 4];
            const int grow = m0 + wm * 64 + i * 16 + row;
            const int gcol2 = n0 + wn * 64 + cc * 4;
            if (gcol2 < CN)                                     // CN%4==0: all-or-nothing
                *(f32x4*)&out[(size_t)grow * CN + gcol2] = v;
        }
    }
}

// Label-column fixup: arccos margin path on exactly B_ROWS elements
__global__ void fixup(const float* __restrict__ norms, const int* __restrict__ label,
                      float* __restrict__ out) {
    const int b = blockIdx.x * 256 + threadIdx.x;
    if (b >= B_ROWS) return;
    const int c = label[b];
    const float safe = fminf(fmaxf(norms[b], 1e-3f), 100.0f);
    const float ms = fminf(fmaxf(safe / (100.0f + 1e-3f) * 0.333f, -1.0f), 1.0f);
    const size_t idx = (size_t)b * CN + c;
    const float cosv = out[idx] * (1.0f / SCALE);        // recover clipped cosine
    float theta = acosf(cosv) + 0.5f * ms;               // + M*ms at label
    theta = fminf(fmaxf(theta, EPSF), 3.14159265358979f - EPSF);
    out[idx] = (cosf(theta) - (0.5f - 0.5f * ms)) * SCALE;  // - (HEAD_B - M*ms), * S
}

extern "C" void kernel_launch(void* const* d_in, const int* in_sizes, int n_in,
                              void* d_out, int out_size, void* d_ws, size_t ws_size,
                              hipStream_t stream) {
    const float* emb   = (const float*)d_in[0];
    const float* norms = (const float*)d_in[1];
    const float* kern  = (const float*)d_in[2];
    const int*   label = (const int*)d_in[3];
    float* out = (float*)d_out;

    ushort_t* embb = (ushort_t*)d_ws;           // B_ROWS*DDIM*2 = 1 MB (only ws use)

    embcast<<<dim3((B_ROWS * DDIM / 4) / 256), 256, 0, stream>>>(emb, embb);
    gemm_fused<<<dim3(1608), 512, 0, stream>>>(embb, kern, out);
    fixup<<<dim3(B_ROWS / 256), 256, 0, stream>>>(norms, label, out);
}

// Round 8
// 389.907 us; speedup vs baseline: 1.0257x; 1.0257x over previous
//
#include <hip/hip_runtime.h>
#include <hip/hip_bf16.h>
#include <math.h>

#define B_ROWS 1024
#define DDIM   512
#define CN     51332
#define CPAD   51456   /* 402 * 128 */
#define EPSF   1e-3f
#define SCALE  64.0f
#define NT     8       /* K-steps of 64 */

typedef unsigned short ushort_t;
typedef short bf16x8 __attribute__((ext_vector_type(8)));   // 8 bf16 (4 VGPRs)
typedef float f32x4  __attribute__((ext_vector_type(4)));   // 4 fp32 acc
typedef unsigned short us8 __attribute__((ext_vector_type(8)));
typedef unsigned short us4 __attribute__((ext_vector_type(4)));

static __device__ __forceinline__ unsigned short f2bf(float f) {
    // round-to-nearest-even fp32 -> bf16 (inputs are finite)
    unsigned int u = __float_as_uint(f);
    u += 0x7fffu + ((u >> 16) & 1u);
    return (unsigned short)(u >> 16);
}

// ---------------------------------------------------------------------------
// Pass 1 (round-3 proven): column sum-of-squares partials + bf16 cast +
// LDS-transpose to [CPAD, DDIM]. 64 cols x 256 d tile via 32 KB LDS.
//   load : lane = col -> 256 B contiguous wave segments, 32 loads in flight.
//   store: half-wave = one col's 512 B d-segment -> contiguous full lines.
//   LDS  : chunk-XOR swizzle (cj ^ col) both sides -> conflict-free b128.
__global__ __launch_bounds__(256) void colpass(const float* __restrict__ kern,
        ushort_t* __restrict__ kbT, float* __restrict__ partials) {
    __shared__ ushort_t tile[64 * 256];        // [col][d-chunk swizzled], 32 KB
    const int c0 = blockIdx.x * 64;
    const int d0 = blockIdx.y * 256;
    const int t  = threadIdx.x;
    const int colL = t & 63;
    const int dg   = t >> 6;                   // 0..3 (== wave id; uniform/wave)
    const int gcol = c0 + colL;
    const bool valid = gcol < CN;
    const int swz = colL & 31;
    float s = 0.f;
#pragma unroll
    for (int h = 0; h < 2; ++h) {
        float v[32];
        const int dh = d0 + dg * 64 + h * 32;
#pragma unroll
        for (int j = 0; j < 32; ++j)
            v[j] = valid ? kern[(size_t)(dh + j) * CN + gcol] : 0.f;
#pragma unroll
        for (int jj = 0; jj < 4; ++jj) {
            us8 pk;
#pragma unroll
            for (int e = 0; e < 8; ++e) {
                const float x = v[jj * 8 + e];
                s += x * x;
                pk[e] = f2bf(x);
            }
            const int cj = dg * 8 + h * 4 + jj;            // 16B chunk, 0..31
            *(us8*)&tile[colL * 256 + ((cj ^ swz) << 3)] = pk;
        }
    }
    partials[(size_t)(blockIdx.y * 4 + dg) * CPAD + gcol] = s;
    __syncthreads();
    const int lane = t & 63;
    const int u = lane & 31, ch = lane >> 5;   // chunk / which col of the pair
#pragma unroll
    for (int p = 0; p < 8; ++p) {
        const int cl = p * 8 + dg * 2 + ch;    // col 0..63
        const us8 val = *(const us8*)&tile[cl * 256 + ((u ^ (cl & 31)) << 3)];
        *(us8*)&kbT[(size_t)(c0 + cl) * DDIM + d0 + u * 8] = val;
    }
}

__global__ void finnorm(const float* __restrict__ partials, float* __restrict__ inv_norm) {
    const int c = blockIdx.x * 256 + threadIdx.x;
    float s = 0.f;
#pragma unroll
    for (int k = 0; k < 8; ++k) s += partials[(size_t)k * CPAD + c];
    inv_norm[c] = 1.0f / fmaxf(sqrtf(s), 1e-5f);
}

__global__ void embcast(const float* __restrict__ emb, ushort_t* __restrict__ embb) {
    const int t = blockIdx.x * 256 + threadIdx.x;    // 4 elems/thread
    const float4 v = ((const float4*)emb)[t];
    us4 o; o[0] = f2bf(v.x); o[1] = f2bf(v.y); o[2] = f2bf(v.z); o[3] = f2bf(v.w);
    *(us4*)&embb[(size_t)t * 4] = o;
}

// ---------------------------------------------------------------------------
// 128x128 counted-vmcnt bf16 MFMA GEMM — the round-2/3 schedule, resized for
// OCCUPANCY. Round-7 counters (fused variant, same 96 KB/1-block layout):
// MfmaUtil 12%, Occupancy 20%, HBM 1.7 TB/s -> latency-bound, every barrier
// stall exposed with 1 block/CU. Fix: 64 KB LDS + VGPR<=128 -> 2 blocks/CU,
// cross-block overlap hides the vmcnt/barrier chain.
//   - BM=BN=128, BK=64, 8 waves (2m x 4n), per-wave 64x32, acc[4][2]=32 VGPR.
//   - LDS 64 KB: A[2][128][64] | B[2][128][64] bf16.
//   - 2 phases/K-step, 8 MFMA each; p0: stage B(t+1)->next (last read t-1.P0,
//     barrier-separated); p1: stage A(t+2)->cur (fully read at t.P0).
//     vmcnt(2) once per K-step retires exactly A(t+1)2+B(t+1)2 (FIFO),
//     leaving A(t+2)2 in flight. Never vmcnt(0) in the loop.
//   - Both-sides chunk-XOR swizzle: linear DMA dest, pre-swizzled global
//     source chunk (c8^r8), ds_read XORs chunk^(row&7) -> conflict-free b128.
#define MFMA(d, va, vb) (d) = __builtin_amdgcn_mfma_f32_16x16x32_bf16((va), (vb), (d), 0, 0, 0)

#define STAGE16(gp, lp) __builtin_amdgcn_global_load_lds( \
    (__attribute__((address_space(1))) void*)(gp), \
    (__attribute__((address_space(3))) void*)(lp), 16, 0, 0)

// gl: per-lane global base (row r8, swizzled chunk); sb: LDS ushort base.
// Stages a 128x64 tile: rows w*16 + r8 + {0,8} per wave.
#define STAGE(gl, sb, kstep) do { \
    const int rb_ = w * 16; \
    STAGE16((gl) + (size_t)rb_ * DDIM + (size_t)(kstep) * 64, &(sb)[rb_ * 64]); \
    STAGE16((gl) + (size_t)(rb_ + 8) * DDIM + (size_t)(kstep) * 64, &(sb)[(rb_ + 8) * 64]); \
} while (0)

__global__ __launch_bounds__(512, 4) void gemm_kernel(
        const ushort_t* __restrict__ embb, const ushort_t* __restrict__ kbT,
        const float* __restrict__ inv_norm, float* __restrict__ out) {
    __shared__ ushort_t smem[32768];    // 64 KB: A[2][8192] | B[2][8192] (ushorts)

    const int tid  = threadIdx.x;
    const int lane = tid & 63;
    const int w    = tid >> 6;                 // wave 0..7
    const int wm = w >> 2, wn = w & 3;         // 2m x 4n wave grid
    const int lm = lane & 15, lq = lane >> 4;  // MFMA row-sel / quad
    const int r8 = lane >> 3, c8 = lane & 7;   // staging lane -> (row, 16B chunk)

    // exact XCD swizzle: 3216 = 8 x 402; m-fast so 8 consecutive blocks in an
    // XCD share one B-panel (128 KB << 4 MB XCD L2).
    const int bid = blockIdx.x;
    const int u   = (bid & 7) * 402 + (bid >> 3);
    const int m0  = (u & 7) * 128;             // 8 m-tiles
    const int n0  = (u >> 3) * 128;            // 402 n-tiles

    const ushort_t* gAl = embb + (size_t)(m0 + r8) * DDIM + ((c8 ^ r8) << 3);
    const ushort_t* gBl = kbT  + (size_t)(n0 + r8) * DDIM + ((c8 ^ r8) << 3);
    const int swz = lm & 7;
    const int ca0 = ((lq    ) ^ swz) << 3;
    const int ca1 = ((lq + 4) ^ swz) << 3;
    const int offA = (wm * 64 + lm) * 64;
    const int offB = (wn * 32 + lm) * 64;

    f32x4 acc[4][2];
#pragma unroll
    for (int i = 0; i < 4; ++i)
#pragma unroll
        for (int j = 0; j < 2; ++j) acc[i][j] = (f32x4){0.f, 0.f, 0.f, 0.f};

    ushort_t* A0 = smem;             // A bufs: 8192 ushorts each (16 KB)
    ushort_t* A1 = smem + 8192;
    ushort_t* B0 = smem + 16384;     // B bufs: 8192 ushorts each
    ushort_t* B1 = smem + 24576;

    // prologue FIFO: [A0 2, B0 2, A1 2]; vmcnt(2) retires A0,B0; B(1) is
    // staged in-loop at t=0.P0.
    STAGE(gAl, A0, 0);
    STAGE(gBl, B0, 0);
    STAGE(gAl, A1, 1);
    asm volatile("s_waitcnt vmcnt(2)" ::: "memory");
    __builtin_amdgcn_s_barrier();
    __builtin_amdgcn_sched_barrier(0);

    for (int t = 0; t < NT; ++t) {
        const int cur = t & 1;
        ushort_t* Sa  = cur ? A1 : A0;
        ushort_t* Sb  = cur ? B1 : B0;
        ushort_t* SbN = cur ? B0 : B1;
        const int kA = (t + 2) & 7;   // wrapped near the end: harmless restage,
        const int kB = (t + 1) & 7;   // keeps vmcnt counts uniform

        bf16x8 a[4][2], b[2][2];
        // ---- phase 0: ds-read all frags | stage B(t+1)->next | MFMA j=0
#pragma unroll
        for (int i = 0; i < 4; ++i) {
            a[i][0] = *(const bf16x8*)&Sa[offA + i * 1024 + ca0];
            a[i][1] = *(const bf16x8*)&Sa[offA + i * 1024 + ca1];
        }
#pragma unroll
        for (int j = 0; j < 2; ++j) {
            b[j][0] = *(const bf16x8*)&Sb[offB + j * 1024 + ca0];
            b[j][1] = *(const bf16x8*)&Sb[offB + j * 1024 + ca1];
        }
        STAGE(gBl, SbN, kB);
        __builtin_amdgcn_s_barrier();
        __builtin_amdgcn_s_setprio(1);
#pragma unroll
        for (int i = 0; i < 4; ++i) {
            MFMA(acc[i][0], a[i][0], b[0][0]);
            MFMA(acc[i][0], a[i][1], b[0][1]);
        }
        __builtin_amdgcn_s_setprio(0);
        __builtin_amdgcn_s_barrier();
        __builtin_amdgcn_sched_barrier(0);

        // ---- phase 1: stage A(t+2)->cur | MFMA j=1 | vmcnt(2)
        STAGE(gAl, Sa, kA);
        __builtin_amdgcn_s_barrier();
        __builtin_amdgcn_s_setprio(1);
#pragma unroll
        for (int i = 0; i < 4; ++i) {
            MFMA(acc[i][1], a[i][0], b[1][0]);
            MFMA(acc[i][1], a[i][1], b[1][1]);
        }
        __builtin_amdgcn_s_setprio(0);
        asm volatile("s_waitcnt vmcnt(2)" ::: "memory");
        __builtin_amdgcn_s_barrier();
        __builtin_amdgcn_sched_barrier(0);
    }

    // ---- epilogue: drain DMA, wave-private swizzled LDS staging (2 KiB/wave,
    // no barriers: cross-lane within one wave only) -> coalesced 16B stores.
    asm volatile("s_waitcnt vmcnt(0)" ::: "memory");
    __syncthreads();

    float invn[2];
#pragma unroll
    for (int j = 0; j < 2; ++j) {
        const int col = n0 + wn * 32 + j * 16 + lm;
        invn[j] = (col < CN) ? inv_norm[col] : 0.f;
    }
    float* Ew = (float*)smem + w * 512;         // 16 x 32 f32, swizzled
#pragma unroll
    for (int i = 0; i < 4; ++i) {
#pragma unroll
        for (int j = 0; j < 2; ++j)
#pragma unroll
            for (int r = 0; r < 4; ++r) {
                const int row = lq * 4 + r;                     // 0..15
                const int cs  = ((j * 16 + lm) + row * 4) & 31; // swizzle
                float v = acc[i][j][r] * invn[j];
                v = fminf(fmaxf(v, -(1.0f - EPSF)), 1.0f - EPSF) * SCALE;
                Ew[row * 32 + cs] = v;
            }
#pragma unroll
        for (int rep = 0; rep < 2; ++rep) {
            const int idx = rep * 64 + lane;                    // 0..127
            const int row = idx >> 3, uu = idx & 7;
            const int us_ = (uu + row) & 7;                     // unswizzle
            const f32x4 v = *(const f32x4*)&Ew[row * 32 + us_ * 4];
            const int grow = m0 + wm * 64 + i * 16 + row;
            const int gcol = n0 + wn * 32 + uu * 4;
            if (gcol < CN)                                      // CN%4==0: all-or-nothing
                *(f32x4*)&out[(size_t)grow * CN + gcol] = v;
        }
    }
}

// Label-column fixup: arccos margin path on exactly B_ROWS elements
__global__ void fixup(const float* __restrict__ norms, const int* __restrict__ label,
                      float* __restrict__ out) {
    const int b = blockIdx.x * 256 + threadIdx.x;
    if (b >= B_ROWS) return;
    const int c = label[b];
    const float safe = fminf(fmaxf(norms[b], 1e-3f), 100.0f);
    const float ms = fminf(fmaxf(safe / (100.0f + 1e-3f) * 0.333f, -1.0f), 1.0f);
    const size_t idx = (size_t)b * CN + c;
    const float cosv = out[idx] * (1.0f / SCALE);        // recover clipped cosine
    float theta = acosf(cosv) + 0.5f * ms;               // + M*ms at label
    theta = fminf(fmaxf(theta, EPSF), 3.14159265358979f - EPSF);
    out[idx] = (cosf(theta) - (0.5f - 0.5f * ms)) * SCALE;  // - (HEAD_B - M*ms), * S
}

extern "C" void kernel_launch(void* const* d_in, const int* in_sizes, int n_in,
                              void* d_out, int out_size, void* d_ws, size_t ws_size,
                              hipStream_t stream) {
    const float* emb   = (const float*)d_in[0];
    const float* norms = (const float*)d_in[1];
    const float* kern  = (const float*)d_in[2];
    const int*   label = (const int*)d_in[3];
    float* out = (float*)d_out;

    char* ws = (char*)d_ws;
    ushort_t* kbT = (ushort_t*)ws;                           // CPAD*DDIM*2 = 52,690,944 B
    size_t off = (size_t)CPAD * DDIM * 2;
    ushort_t* embb = (ushort_t*)(ws + off); off += (size_t)B_ROWS * DDIM * 2;
    float* inv_norm = (float*)(ws + off);   off += (size_t)CPAD * 4;
    float* partials = (float*)(ws + off);   // 8*CPAD*4 B ; total ~55.6 MB

    colpass<<<dim3(CPAD / 64, 2), 256, 0, stream>>>(kern, kbT, partials);
    embcast<<<dim3((B_ROWS * DDIM / 4) / 256), 256, 0, stream>>>(emb, embb);
    finnorm<<<dim3(CPAD / 256), 256, 0, stream>>>(partials, inv_norm);
    gemm_kernel<<<dim3(3216), 512, 0, stream>>>(embb, kbT, inv_norm, out);
    fixup<<<dim3(B_ROWS / 256), 256, 0, stream>>>(norms, label, out);
}